// Round 5
// baseline (393.700 us; speedup 1.0000x reference)
//
#include <hip/hip_runtime.h>

// Trilinear grid interpolation — two-pass: global slab compaction + pinned gather.
//   velocity: [B, 3, G, G, G] f32, points: [B, N, 3] f32, bb: [3,2] f32
//   out: [B, N, 3] f32
//
// R1: u-slab (16 planes, 3 MB) -> XCD L2 pinning via blockIdx%8: fetch 2.1GB->475MB.
// R3: float2 w-pair gathers: 24->12 addresses/point (only -30us => gathers minor).
// R4: the 8x-redundant broadcast scan was the real cost (~300us of wave-level
//     work at 1/8 lane efficiency). Pass 1 compacts point indices into
//     per-(batch,slab) lists in d_ws (one scan total); pass 2 gathers with
//     full lanes on the slab's XCD. Falls back to R3 kernel if ws too small.

constexpr int G = 128;
constexpr long long G3 = (long long)G * G * G;
constexpr int NSLAB = 8;   // == #XCDs

// ---------------- Pass 1: compaction ----------------
__global__ __launch_bounds__(256) void compact_kernel(
    const float* __restrict__ pts,   // [B,N,3]
    const float* __restrict__ bb,    // [3,2]
    int* __restrict__ gcnt,          // [B*8]
    int* __restrict__ list,          // [B*8][N]
    int N, int nchunk)
{
    __shared__ int h[NSLAB];
    __shared__ int sbase[NSLAB];

    int bid = blockIdx.x;
    int c = bid % nchunk;
    int b = bid / nchunk;

    if (threadIdx.x < NSLAB) h[threadIdx.x] = 0;
    __syncthreads();

    int n = c * 256 + threadIdx.x;
    int slab = -1, pos = 0;
    if (n < N) {
        float bx0 = bb[0], bx1 = bb[1];
        const float Gm1 = (float)(G - 1);
        float px = pts[((long long)b * N + n) * 3];
        float u = (px - bx0) / (bx1 - bx0) * Gm1;
        float fu = fminf(fmaxf(floorf(u), 0.f), Gm1);
        slab = ((int)fu) >> 4;
        pos = atomicAdd(&h[slab], 1);
    }
    __syncthreads();
    if (threadIdx.x < NSLAB)
        sbase[threadIdx.x] = atomicAdd(&gcnt[b * NSLAB + threadIdx.x], h[threadIdx.x]);
    __syncthreads();
    if (slab >= 0)
        list[((long long)(b * NSLAB + slab)) * N + sbase[slab] + pos] = n;
}

// ---------------- Pass 2: full-lane pinned gather ----------------
__global__ __launch_bounds__(256) void trilerp_gather_kernel(
    const float* __restrict__ vel,   // [B,3,G,G,G]
    const float* __restrict__ pts,   // [B,N,3]
    const float* __restrict__ bb,    // [3,2]
    const int* __restrict__ gcnt,    // [B*8]
    const int* __restrict__ list,    // [B*8][N]
    float* __restrict__ out,         // [B,N,3]
    int N, int nchunk)
{
    int bid  = blockIdx.x;
    int slab = bid & (NSLAB - 1);
    int t    = bid >> 3;
    int c    = t % nchunk;
    int b    = t / nchunk;

    int cnt = gcnt[b * NSLAB + slab];
    int i = c * 256 + threadIdx.x;
    if (i >= cnt) return;

    int n = list[((long long)(b * NSLAB + slab)) * N + i];

    float bx0 = bb[0], bx1 = bb[1];
    float by0 = bb[2], by1 = bb[3];
    float bz0 = bb[4], bz1 = bb[5];

    long long pi = (long long)b * N + n;
    const float* p = pts + pi * 3;
    float px = p[0], py = p[1], pz = p[2];

    const float Gm1 = (float)(G - 1);
    float u = (px - bx0) / (bx1 - bx0) * Gm1;
    float v = (py - by0) / (by1 - by0) * Gm1;
    float w = (pz - bz0) / (bz1 - bz0) * Gm1;

    float fu = fminf(fmaxf(floorf(u), 0.f), Gm1);
    float fv = fminf(fmaxf(floorf(v), 0.f), Gm1);
    float fw = fminf(fmaxf(floorf(w), 0.f), Gm1);

    float du = u - fu, dv = v - fv, dw = w - fw;   // frac
    float gu = fu + 1.0f - u;                      // gfrac
    float gv = fv + 1.0f - v;
    float gw = fw + 1.0f - w;

    int iu1 = (int)fu, iv1 = (int)fv, iw1 = (int)fw;
    int iu2 = min(iu1 + 1, G - 1);
    int iv2 = min(iv1 + 1, G - 1);

    int iwb = min(iw1, G - 2);        // float2 base along w
    bool lo = (iw1 <= G - 2);

    float w11 = gu * gv, w12 = gu * dv, w21 = du * gv, w22 = du * dv;

    const float* vb = vel + (long long)b * 3 * G3;

    long long o11 = (long long)((iu1 << 7) + iv1) * G + iwb;
    long long o12 = (long long)((iu1 << 7) + iv2) * G + iwb;
    long long o21 = (long long)((iu2 << 7) + iv1) * G + iwb;
    long long o22 = (long long)((iu2 << 7) + iv2) * G + iwb;

    float o[3];
    #pragma unroll
    for (int ch = 0; ch < 3; ++ch) {
        const float* vc = vb + (long long)ch * G3;
        float2 p11 = *reinterpret_cast<const float2*>(vc + o11);
        float2 p12 = *reinterpret_cast<const float2*>(vc + o12);
        float2 p21 = *reinterpret_cast<const float2*>(vc + o21);
        float2 p22 = *reinterpret_cast<const float2*>(vc + o22);
        float a11 = lo ? p11.x : p11.y;
        float a12 = lo ? p12.x : p12.y;
        float a21 = lo ? p21.x : p21.y;
        float a22 = lo ? p22.x : p22.y;
        o[ch] = w11 * (gw * a11 + dw * p11.y)
              + w12 * (gw * a12 + dw * p12.y)
              + w21 * (gw * a21 + dw * p21.y)
              + w22 * (gw * a22 + dw * p22.y);
    }

    float* op = out + pi * 3;
    op[0] = o[0]; op[1] = o[1]; op[2] = o[2];
}

// ---------------- Fallback (R3): broadcast scan, no workspace ----------------
__global__ __launch_bounds__(256) void trilerp_pair_kernel(
    const float* __restrict__ vel, const float* __restrict__ pts,
    const float* __restrict__ bb, float* __restrict__ out,
    int N, int nchunk)
{
    int bid  = blockIdx.x;
    int slab = bid & (NSLAB - 1);
    int t    = bid >> 3;
    int c    = t % nchunk;
    int b    = t / nchunk;
    int n = c * 256 + threadIdx.x;
    if (n >= N) return;

    float bx0 = bb[0], bx1 = bb[1];
    float by0 = bb[2], by1 = bb[3];
    float bz0 = bb[4], bz1 = bb[5];
    long long pi = (long long)b * N + n;
    const float* p = pts + pi * 3;
    float px = p[0], py = p[1], pz = p[2];
    const float Gm1 = (float)(G - 1);
    float u = (px - bx0) / (bx1 - bx0) * Gm1;
    float fu = fminf(fmaxf(floorf(u), 0.f), Gm1);
    int iu1 = (int)fu;
    if ((iu1 >> 4) != slab) return;
    float v = (py - by0) / (by1 - by0) * Gm1;
    float w = (pz - bz0) / (bz1 - bz0) * Gm1;
    float fv = fminf(fmaxf(floorf(v), 0.f), Gm1);
    float fw = fminf(fmaxf(floorf(w), 0.f), Gm1);
    float du = u - fu, dv = v - fv, dw = w - fw;
    float gu = fu + 1.0f - u, gv = fv + 1.0f - v, gw = fw + 1.0f - w;
    int iv1 = (int)fv, iw1 = (int)fw;
    int iu2 = min(iu1 + 1, G - 1);
    int iv2 = min(iv1 + 1, G - 1);
    int iwb = min(iw1, G - 2);
    bool lo = (iw1 <= G - 2);
    float w11 = gu * gv, w12 = gu * dv, w21 = du * gv, w22 = du * dv;
    const float* vb = vel + (long long)b * 3 * G3;
    long long o11 = (long long)((iu1 << 7) + iv1) * G + iwb;
    long long o12 = (long long)((iu1 << 7) + iv2) * G + iwb;
    long long o21 = (long long)((iu2 << 7) + iv1) * G + iwb;
    long long o22 = (long long)((iu2 << 7) + iv2) * G + iwb;
    float o[3];
    #pragma unroll
    for (int ch = 0; ch < 3; ++ch) {
        const float* vc = vb + (long long)ch * G3;
        float2 p11 = *reinterpret_cast<const float2*>(vc + o11);
        float2 p12 = *reinterpret_cast<const float2*>(vc + o12);
        float2 p21 = *reinterpret_cast<const float2*>(vc + o21);
        float2 p22 = *reinterpret_cast<const float2*>(vc + o22);
        float a11 = lo ? p11.x : p11.y;
        float a12 = lo ? p12.x : p12.y;
        float a21 = lo ? p21.x : p21.y;
        float a22 = lo ? p22.x : p22.y;
        o[ch] = w11 * (gw * a11 + dw * p11.y)
              + w12 * (gw * a12 + dw * p12.y)
              + w21 * (gw * a21 + dw * p21.y)
              + w22 * (gw * a22 + dw * p22.y);
    }
    float* op = out + pi * 3;
    op[0] = o[0]; op[1] = o[1]; op[2] = o[2];
}

extern "C" void kernel_launch(void* const* d_in, const int* in_sizes, int n_in,
                              void* d_out, int out_size, void* d_ws, size_t ws_size,
                              hipStream_t stream) {
    const float* vel = (const float*)d_in[0];
    const float* pts = (const float*)d_in[1];
    const float* bb  = (const float*)d_in[2];
    float* out = (float*)d_out;

    int B = (int)(in_sizes[0] / (3 * G3));       // 16
    int N = in_sizes[1] / (3 * B);               // 200000

    int nchunk = (N + 255) / 256;                // 782

    size_t cnt_bytes  = (size_t)B * NSLAB * sizeof(int);
    size_t list_off   = 1024;                     // counters at 0, lists at 1KB
    size_t list_bytes = (size_t)B * NSLAB * N * sizeof(int);

    if (ws_size >= list_off + list_bytes) {
        int* gcnt = (int*)d_ws;
        int* list = (int*)((char*)d_ws + list_off);
        hipMemsetAsync(gcnt, 0, cnt_bytes, stream);
        compact_kernel<<<B * nchunk, 256, 0, stream>>>(pts, bb, gcnt, list, N, nchunk);
        long long blocks2 = (long long)B * nchunk * NSLAB;
        trilerp_gather_kernel<<<(int)blocks2, 256, 0, stream>>>(
            vel, pts, bb, gcnt, list, out, N, nchunk);
    } else {
        long long blocks = (long long)B * nchunk * NSLAB;
        trilerp_pair_kernel<<<(int)blocks, 256, 0, stream>>>(vel, pts, bb, out, N, nchunk);
    }
}

// Round 6
// 308.200 us; speedup vs baseline: 1.2774x; 1.2774x over previous
//
#include <hip/hip_runtime.h>
#include <hip/hip_fp16.h>

// Trilinear grid interpolation — fp16 channel-packed repack + pinned broadcast gather.
//   velocity: [B, 3, G, G, G] f32, points: [B, N, 3] f32, bb: [3,2] f32
//   out: [B, N, 3] f32
//
// Evidence so far (R1-R4): kernel is bound by L1-miss handling on the
// scattered gathers (~4 cyc/CU per distinct line touched per point); all
// f32 [3][G^3] variants touch ~12.7 lines/point. Lever: channel-pack cells
// to 8B (3xfp16+pad) so one (u,v)-row w-pair = 16B in ONE row -> ~4.5
// lines/point. Slab->XCD L2 pinning (blockIdx%8) kept; broadcast scan kept
// (R4 showed compaction saves nothing). fp16 adds <=0.003 absmax (thr 0.081).

constexpr int G = 128;
constexpr long long G3 = (long long)G * G * G;
constexpr int NSLAB = 8;   // == #XCDs

// ---------------- Pass 1: repack [gb,3,G3] f32 -> [gb,G3] uint2 (3xfp16+pad) ----
__global__ __launch_bounds__(256) void repack_kernel(
    const float* __restrict__ vel,   // [B,3,G,G,G]
    uint2* __restrict__ grid8,       // [gb,G3] cells of 8B
    int b0)
{
    long long t = (long long)blockIdx.x * 256 + threadIdx.x;  // 4-cell unit
    long long cell4 = t * 4;
    int bw = (int)(cell4 / G3);
    int ci = (int)(cell4 % G3);     // G3 % 4 == 0: float4 never crosses batch
    long long vbase = ((long long)(b0 + bw) * 3) * G3;

    float4 v0 = *reinterpret_cast<const float4*>(vel + vbase + ci);
    float4 v1 = *reinterpret_cast<const float4*>(vel + vbase + G3 + ci);
    float4 v2 = *reinterpret_cast<const float4*>(vel + vbase + 2 * G3 + ci);

    auto pk = [](float a, float b) -> unsigned int {
        unsigned int ua = __half_as_ushort(__float2half(a));
        unsigned int ub = __half_as_ushort(__float2half(b));
        return ua | (ub << 16);
    };
    auto pq = [](float c) -> unsigned int {
        return (unsigned int)__half_as_ushort(__float2half(c));
    };

    uint4 d0, d1;
    d0.x = pk(v0.x, v1.x); d0.y = pq(v2.x);
    d0.z = pk(v0.y, v1.y); d0.w = pq(v2.y);
    d1.x = pk(v0.z, v1.z); d1.y = pq(v2.z);
    d1.z = pk(v0.w, v1.w); d1.w = pq(v2.w);

    uint4* dst = reinterpret_cast<uint4*>(grid8 + (long long)bw * G3 + ci);
    dst[0] = d0;
    dst[1] = d1;
}

// ---------------- Pass 2: pinned broadcast gather on packed grid ----------------
__global__ __launch_bounds__(256) void trilerp_packed_kernel(
    const uint2* __restrict__ grid8, // [gb,G3]
    const float* __restrict__ pts,   // [B,N,3]
    const float* __restrict__ bb,    // [3,2]
    float* __restrict__ out,         // [B,N,3]
    int N, int nchunk, int b0)
{
    int bid  = blockIdx.x;
    int slab = bid & (NSLAB - 1);
    int t    = bid >> 3;
    int c    = t % nchunk;           // chunk within batch
    int bw   = t / nchunk;           // batch within group
    int b    = b0 + bw;

    int n = c * 256 + threadIdx.x;
    if (n >= N) return;

    float bx0 = bb[0], bx1 = bb[1];
    float by0 = bb[2], by1 = bb[3];
    float bz0 = bb[4], bz1 = bb[5];

    long long pi = (long long)b * N + n;
    const float* p = pts + pi * 3;
    float px = p[0], py = p[1], pz = p[2];

    const float Gm1 = (float)(G - 1);
    float u = (px - bx0) / (bx1 - bx0) * Gm1;

    float fu = fminf(fmaxf(floorf(u), 0.f), Gm1);
    int iu1 = (int)fu;
    if ((iu1 >> 4) != slab) return;   // not this XCD's slab

    float v = (py - by0) / (by1 - by0) * Gm1;
    float w = (pz - bz0) / (bz1 - bz0) * Gm1;
    float fv = fminf(fmaxf(floorf(v), 0.f), Gm1);
    float fw = fminf(fmaxf(floorf(w), 0.f), Gm1);

    float du = u - fu, dv = v - fv, dw = w - fw;   // frac
    float gu = fu + 1.0f - u;                      // gfrac
    float gv = fv + 1.0f - v;
    float gw = fw + 1.0f - w;

    int iv1 = (int)fv, iw1 = (int)fw;
    int iu2 = min(iu1 + 1, G - 1);
    int iv2 = min(iv1 + 1, G - 1);

    int iwb = min(iw1, G - 2);        // pair base along w
    bool lo = (iw1 <= G - 2);         // tap1 = lo ? cell(iwb) : cell(iwb+1)

    float w11 = gu * gv, w12 = gu * dv, w21 = du * gv, w22 = du * dv;

    long long gb = (long long)bw * G3;
    long long o11 = gb + (((iu1 << 7) + iv1) << 7) + iwb;
    long long o12 = gb + (((iu1 << 7) + iv2) << 7) + iwb;
    long long o21 = gb + (((iu2 << 7) + iv1) << 7) + iwb;
    long long o22 = gb + (((iu2 << 7) + iv2) << 7) + iwb;

    // 8 independent 8B loads (4 row-pairs x {w, w+1})
    uint2 L11 = grid8[o11], H11 = grid8[o11 + 1];
    uint2 L12 = grid8[o12], H12 = grid8[o12 + 1];
    uint2 L21 = grid8[o21], H21 = grid8[o21 + 1];
    uint2 L22 = grid8[o22], H22 = grid8[o22 + 1];

    auto ch = [](const uint2& q, int k) -> float {
        unsigned short us = (k == 0) ? (unsigned short)(q.x & 0xffff)
                        : (k == 1) ? (unsigned short)(q.x >> 16)
                                   : (unsigned short)(q.y & 0xffff);
        return __half2float(__ushort_as_half(us));
    };

    float o[3];
    #pragma unroll
    for (int k = 0; k < 3; ++k) {
        float a11 = lo ? ch(L11, k) : ch(H11, k);
        float a12 = lo ? ch(L12, k) : ch(H12, k);
        float a21 = lo ? ch(L21, k) : ch(H21, k);
        float a22 = lo ? ch(L22, k) : ch(H22, k);
        o[k] = w11 * (gw * a11 + dw * ch(H11, k))
             + w12 * (gw * a12 + dw * ch(H12, k))
             + w21 * (gw * a21 + dw * ch(H21, k))
             + w22 * (gw * a22 + dw * ch(H22, k));
    }

    float* op = out + pi * 3;
    op[0] = o[0]; op[1] = o[1]; op[2] = o[2];
}

// ---------------- Fallback (R3): f32 broadcast scan, no workspace ----------------
__global__ __launch_bounds__(256) void trilerp_pair_kernel(
    const float* __restrict__ vel, const float* __restrict__ pts,
    const float* __restrict__ bb, float* __restrict__ out,
    int N, int nchunk)
{
    int bid  = blockIdx.x;
    int slab = bid & (NSLAB - 1);
    int t    = bid >> 3;
    int c    = t % nchunk;
    int b    = t / nchunk;
    int n = c * 256 + threadIdx.x;
    if (n >= N) return;

    float bx0 = bb[0], bx1 = bb[1];
    float by0 = bb[2], by1 = bb[3];
    float bz0 = bb[4], bz1 = bb[5];
    long long pi = (long long)b * N + n;
    const float* p = pts + pi * 3;
    float px = p[0], py = p[1], pz = p[2];
    const float Gm1 = (float)(G - 1);
    float u = (px - bx0) / (bx1 - bx0) * Gm1;
    float fu = fminf(fmaxf(floorf(u), 0.f), Gm1);
    int iu1 = (int)fu;
    if ((iu1 >> 4) != slab) return;
    float v = (py - by0) / (by1 - by0) * Gm1;
    float w = (pz - bz0) / (bz1 - bz0) * Gm1;
    float fv = fminf(fmaxf(floorf(v), 0.f), Gm1);
    float fw = fminf(fmaxf(floorf(w), 0.f), Gm1);
    float du = u - fu, dv = v - fv, dw = w - fw;
    float gu = fu + 1.0f - u, gv = fv + 1.0f - v, gw = fw + 1.0f - w;
    int iv1 = (int)fv, iw1 = (int)fw;
    int iu2 = min(iu1 + 1, G - 1);
    int iv2 = min(iv1 + 1, G - 1);
    int iwb = min(iw1, G - 2);
    bool lo = (iw1 <= G - 2);
    float w11 = gu * gv, w12 = gu * dv, w21 = du * gv, w22 = du * dv;
    const float* vb = vel + (long long)b * 3 * G3;
    long long o11 = (long long)((iu1 << 7) + iv1) * G + iwb;
    long long o12 = (long long)((iu1 << 7) + iv2) * G + iwb;
    long long o21 = (long long)((iu2 << 7) + iv1) * G + iwb;
    long long o22 = (long long)((iu2 << 7) + iv2) * G + iwb;
    float o[3];
    #pragma unroll
    for (int chn = 0; chn < 3; ++chn) {
        const float* vc = vb + (long long)chn * G3;
        float2 p11 = *reinterpret_cast<const float2*>(vc + o11);
        float2 p12 = *reinterpret_cast<const float2*>(vc + o12);
        float2 p21 = *reinterpret_cast<const float2*>(vc + o21);
        float2 p22 = *reinterpret_cast<const float2*>(vc + o22);
        float a11 = lo ? p11.x : p11.y;
        float a12 = lo ? p12.x : p12.y;
        float a21 = lo ? p21.x : p21.y;
        float a22 = lo ? p22.x : p22.y;
        o[chn] = w11 * (gw * a11 + dw * p11.y)
               + w12 * (gw * a12 + dw * p12.y)
               + w21 * (gw * a21 + dw * p21.y)
               + w22 * (gw * a22 + dw * p22.y);
    }
    float* op = out + pi * 3;
    op[0] = o[0]; op[1] = o[1]; op[2] = o[2];
}

extern "C" void kernel_launch(void* const* d_in, const int* in_sizes, int n_in,
                              void* d_out, int out_size, void* d_ws, size_t ws_size,
                              hipStream_t stream) {
    const float* vel = (const float*)d_in[0];
    const float* pts = (const float*)d_in[1];
    const float* bb  = (const float*)d_in[2];
    float* out = (float*)d_out;

    int B = (int)(in_sizes[0] / (3 * G3));       // 16
    int N = in_sizes[1] / (3 * B);               // 200000
    int nchunk = (N + 255) / 256;                // 782

    size_t per_batch = (size_t)G3 * 8;           // 16.8 MB packed grid per batch
    int g = (int)(ws_size / per_batch);
    if (g > B) g = B;

    if (g >= 1) {
        uint2* grid8 = (uint2*)d_ws;
        for (int b0 = 0; b0 < B; b0 += g) {
            int gb = (B - b0 < g) ? (B - b0) : g;
            long long rblocks = (long long)gb * (G3 / 4) / 256;   // gb*2048
            repack_kernel<<<(int)rblocks, 256, 0, stream>>>(vel, grid8, b0);
            long long gblocks = (long long)gb * nchunk * NSLAB;
            trilerp_packed_kernel<<<(int)gblocks, 256, 0, stream>>>(
                grid8, pts, bb, out, N, nchunk, b0);
        }
    } else {
        long long blocks = (long long)B * nchunk * NSLAB;
        trilerp_pair_kernel<<<(int)blocks, 256, 0, stream>>>(vel, pts, bb, out, N, nchunk);
    }
}